// Round 1
// 110.752 us; speedup vs baseline: 1.0556x; 1.0556x over previous
//
#include <hip/hip_runtime.h>
#include <hip/hip_bf16.h>
#include <stdint.h>

typedef short s16x8 __attribute__((ext_vector_type(8)));
typedef float f32x4 __attribute__((ext_vector_type(4)));

static constexpr int DDIM = 256;
static constexpr float TEN_LOG2E = 14.4269504088896340736f; // 10 * log2(e)

using u32_glb = __attribute__((address_space(1))) unsigned int;
using u32_lds = __attribute__((address_space(3))) unsigned int;

// ---------------- Kernel 1: normalize + pack into MFMA-fragment order ----------------
// 512 blocks x 256 threads; block g handles rows [16g, 16g+16). Output layout:
// packed[((g*8 + kt)*64 + lane)*8 .. +8] = bf16 P[16g + (lane&15)][kt*32 + (lane>>4)*8 ..]
// i.e. each (group, kt) fragment is one contiguous 1KB block in exact lane order, so a
// fragment load (or global_load_lds stage) in kernel 2 is a single coalesced
// 16B/lane segment. Also zero-inits row_s[8192] (blocks 0..7) and out[0] (block 0).
__global__ __launch_bounds__(256) void normalize_pack_kernel(
    const float* __restrict__ zi, const float* __restrict__ zj,
    ushort* __restrict__ packed, float* __restrict__ row_s, float* __restrict__ out)
{
    __shared__ ushort lds[16 * 256];

    if (blockIdx.x < 8) {
        ((float4*)row_s)[blockIdx.x * 256 + threadIdx.x] = (float4){0.f, 0.f, 0.f, 0.f};
        if (blockIdx.x == 0 && threadIdx.x == 0) out[0] = 0.0f;
    }

    const int t = threadIdx.x;
    const int r = t >> 4;            // 0..15: row within group
    const int c = t & 15;            // 16 threads per row
    const int row = blockIdx.x * 16 + r;
    const float* src = (row < 4096) ? (zi + (size_t)row * DDIM)
                                    : (zj + (size_t)(row - 4096) * DDIM);
    float4 v[4];
    #pragma unroll
    for (int j = 0; j < 4; ++j) v[j] = ((const float4*)src)[c + j * 16];

    float ss = 0.0f;
    #pragma unroll
    for (int j = 0; j < 4; ++j)
        ss += v[j].x * v[j].x + v[j].y * v[j].y + v[j].z * v[j].z + v[j].w * v[j].w;
    // reduce across the 16 lanes of this row (lanes of a row are contiguous)
    ss += __shfl_xor(ss, 1, 64);
    ss += __shfl_xor(ss, 2, 64);
    ss += __shfl_xor(ss, 4, 64);
    ss += __shfl_xor(ss, 8, 64);
    const float inv = 1.0f / fmaxf(sqrtf(ss), 1e-8f);

    #pragma unroll
    for (int j = 0; j < 4; ++j) {
        ushort4 o;
        o.x = __builtin_bit_cast(unsigned short, __float2bfloat16(v[j].x * inv));
        o.y = __builtin_bit_cast(unsigned short, __float2bfloat16(v[j].y * inv));
        o.z = __builtin_bit_cast(unsigned short, __float2bfloat16(v[j].z * inv));
        o.w = __builtin_bit_cast(unsigned short, __float2bfloat16(v[j].w * inv));
        *(ushort4*)(lds + r * 256 + (c + j * 16) * 4) = o;
    }
    __syncthreads();

    // repack: 8 kt x 64 lanes = 512 fragment-slots of 16B per block; 2 per thread
    #pragma unroll
    for (int h = 0; h < 2; ++h) {
        const int idx  = h * 256 + t;
        const int kt   = idx >> 6;
        const int lane = idx & 63;
        const int q    = lane >> 4;
        const int l15  = lane & 15;
        s16x8 frag = *(const s16x8*)(lds + l15 * 256 + kt * 32 + q * 8);
        ((s16x8*)packed)[(size_t)(blockIdx.x * 8 + kt) * 64 + lane] = frag;
    }
}

// ---------------- Kernel 2: upper-triangle Gram tiles, LDS double-buffered ----------
// 2080 blocks = 64*65/2 tiles of 128x128; 4 waves x (64x64 via 16x16x32 MFMA, 4x4
// frags). m97-style pipeline: global_load_lds (16B) stages kt+1's 16 fragments (8 A +
// 8 B, 16KB) into LDS buffer ^1 while the waves ds_read_b128 + MFMA from the current
// buffer; one __syncthreads per kt drains vmcnt and flips buffers. The packed array is
// already in exact lane order per fragment, so the wave-uniform-base+lane*16 LDS write
// of global_load_lds lands each fragment linearly — no swizzle needed, and the
// ds_read_b128 at base+lane*16 is the conflict-free pattern. Panels are shared by all
// 4 waves (halves L2 traffic vs per-wave direct loads).
// Epilogue: row/col partials merged in LDS first; one global atomic per row + per col.
__global__ __launch_bounds__(256) void simexp_kernel(
    const ushort* __restrict__ packed,
    float* __restrict__ row_s,
    float* __restrict__ pos_out)
{
    // [buf][frag 0..15][512 ushorts = 1KB]; frags 0..7 = A groups, 8..15 = B groups
    __shared__ ushort sbuf[2][16][512];
    __shared__ float rsum_s[128];
    __shared__ float csum_s[128];

    const int tid  = threadIdx.x;
    const int w    = tid >> 6;
    const int lane = tid & 63;
    const int q    = lane >> 4;      // 0..3: K-octet / row-quad of the MFMA operand
    const int l15  = lane & 15;
    const int wm   = (w >> 1) * 64;  // wave row offset in 128x128 tile
    const int wn   = (w & 1) * 64;   // wave col offset

    // ---- upper-triangle decode: block b -> (ti, tj), ti <= tj ----
    const int b = blockIdx.x;
    int ti = (int)(64.5f - sqrtf(64.5f * 64.5f - 2.0f * (float)b));
    while ((ti + 1) * 64 - ((ti + 1) * ti) / 2 <= b) ++ti;
    while (ti * 64 - (ti * (ti - 1)) / 2 > b) --ti;
    const int tj = ti + (b - (ti * 64 - (ti * (ti - 1)) / 2));
    const int r0 = ti * 128, c0 = tj * 128;
    const bool diag  = (ti == tj);
    const bool ptile = (tj == ti + 32);  // contains positive-pair diagonal

    if (tid < 128) rsum_s[tid] = 0.0f;
    else           csum_s[tid - 128] = 0.0f;

    // per-wave staging sources: wave w stages fragments f = 4w..4w+3
    // f<8 -> A group (r0>>4)+f ; f>=8 -> B group (c0>>4)+(f-8)
    const int gA = r0 >> 4;
    const int gB = c0 >> 4;
    const ushort* sbase[4];
    #pragma unroll
    for (int s = 0; s < 4; ++s) {
        const int f = w * 4 + s;
        const int g = (f < 8) ? (gA + f) : (gB + (f - 8));
        sbase[s] = packed + (size_t)(g * 8) * 512 + (size_t)lane * 8;  // kt=0 fragment
    }

    auto stage = [&](int buf, int kt) {
        #pragma unroll
        for (int s = 0; s < 4; ++s) {
            const int f = w * 4 + s;
            __builtin_amdgcn_global_load_lds(
                (const u32_glb*)(sbase[s] + kt * 512),
                (u32_lds*)&sbuf[buf][f][0],
                16, 0, 0);
        }
    };

    f32x4 acc[4][4];
    #pragma unroll
    for (int mi = 0; mi < 4; ++mi)
        #pragma unroll
        for (int ni = 0; ni < 4; ++ni)
            acc[mi][ni] = (f32x4){0.f, 0.f, 0.f, 0.f};

    stage(0, 0);
    __syncthreads();   // drains vmcnt(0): buffer 0 ready (also covers rsum_s init)

    const int fa0 = (w >> 1) * 4;      // this wave's A fragment base
    const int fb0 = 8 + (w & 1) * 4;   // this wave's B fragment base

    for (int kt = 0; kt < 8; ++kt) {
        const int cur = kt & 1;
        if (kt < 7) stage(cur ^ 1, kt + 1);   // next tile's loads fly under the MFMAs

        s16x8 af[4], bfr[4];
        #pragma unroll
        for (int mi = 0; mi < 4; ++mi)
            af[mi] = *(const s16x8*)&sbuf[cur][fa0 + mi][lane * 8];
        #pragma unroll
        for (int ni = 0; ni < 4; ++ni)
            bfr[ni] = *(const s16x8*)&sbuf[cur][fb0 + ni][lane * 8];

        #pragma unroll
        for (int mi = 0; mi < 4; ++mi)
            #pragma unroll
            for (int ni = 0; ni < 4; ++ni)
                acc[mi][ni] = __builtin_amdgcn_mfma_f32_16x16x32_bf16(
                    af[mi], bfr[ni], acc[mi][ni], 0, 0, 0);

        __syncthreads();  // all reads of cur done + staged cur^1 landed (vmcnt drain)
    }

    // ---- epilogue: exp, diag mask, positive extraction, row+col sums ----
    // C/D layout (16x16): col = lane&15, row = q*4 + r
    float rsum[4][4];
    float csum[4] = {0.f, 0.f, 0.f, 0.f};
    #pragma unroll
    for (int mi = 0; mi < 4; ++mi)
        #pragma unroll
        for (int r = 0; r < 4; ++r) rsum[mi][r] = 0.0f;

    #pragma unroll
    for (int mi = 0; mi < 4; ++mi)
        #pragma unroll
        for (int ni = 0; ni < 4; ++ni)
            #pragma unroll
            for (int r = 0; r < 4; ++r) {
                const int lr = wm + mi * 16 + q * 4 + r;
                const int lc = wn + ni * 16 + l15;
                float e = exp2f(acc[mi][ni][r] * TEN_LOG2E);
                if (diag && lr == lc) e = 0.0f;          // mask self-similarity
                rsum[mi][r] += e;
                csum[ni]    += e;
                if (ptile && lr == lc) {                 // positive pair: col = row + 4096
                    const float v = acc[mi][ni][r] * 10.0f;
                    pos_out[r0 + lr] = v;
                    pos_out[c0 + lr] = v;
                }
            }

    // row partials: reduce across the 16 lanes (cols) of each quad, merge via LDS
    #pragma unroll
    for (int mi = 0; mi < 4; ++mi)
        #pragma unroll
        for (int r = 0; r < 4; ++r) {
            float v = rsum[mi][r];
            v += __shfl_xor(v, 1, 64);
            v += __shfl_xor(v, 2, 64);
            v += __shfl_xor(v, 4, 64);
            v += __shfl_xor(v, 8, 64);
            if (l15 == 0)
                atomicAdd(&rsum_s[wm + mi * 16 + q * 4 + r], v);
        }

    // col partials (symmetric contribution): reduce across quads, merge via LDS
    if (!diag) {
        #pragma unroll
        for (int ni = 0; ni < 4; ++ni) {
            float v = csum[ni];
            v += __shfl_xor(v, 16, 64);
            v += __shfl_xor(v, 32, 64);
            if (q == 0)
                atomicAdd(&csum_s[wn + ni * 16 + l15], v);
        }
    }

    __syncthreads();

    // one global atomic per row (+ per col if off-diagonal): 128..256 lane-atomics/block
    if (tid < 128) {
        atomicAdd(&row_s[r0 + tid], rsum_s[tid]);
    } else if (!diag) {
        atomicAdd(&row_s[c0 + (tid - 128)], csum_s[tid - 128]);
    }
}

// ---------------- Kernel 3: finalize loss ----------------
__global__ __launch_bounds__(256) void finalize_kernel(
    const float* __restrict__ row_s, const float* __restrict__ pos,
    float* __restrict__ out)
{
    const int i = blockIdx.x * 256 + threadIdx.x;   // float4 index, 2048 total
    float4 s = ((const float4*)row_s)[i];
    float4 p = ((const float4*)pos)[i];
    float local = (__logf(s.x) - p.x) + (__logf(s.y) - p.y)
                + (__logf(s.z) - p.z) + (__logf(s.w) - p.w);
    #pragma unroll
    for (int off = 32; off > 0; off >>= 1) local += __shfl_xor(local, off, 64);
    __shared__ float red[4];
    if ((threadIdx.x & 63) == 0) red[threadIdx.x >> 6] = local;
    __syncthreads();
    if (threadIdx.x == 0)
        atomicAdd(out, (red[0] + red[1] + red[2] + red[3]) * (1.0f / 8192.0f));
}

// ---------------- Launch ----------------
extern "C" void kernel_launch(void* const* d_in, const int* in_sizes, int n_in,
                              void* d_out, int out_size, void* d_ws, size_t ws_size,
                              hipStream_t stream)
{
    const float* zi = (const float*)d_in[0];
    const float* zj = (const float*)d_in[1];

    ushort* packed = (ushort*)d_ws;                                    // 4 MB fragment-order bf16
    float* row_s   = (float*)((char*)d_ws + (4u << 20));               // 8192 fp32
    float* pos     = (float*)((char*)d_ws + (4u << 20) + (32u << 10)); // 8192 fp32
    float* out     = (float*)d_out;

    hipLaunchKernelGGL(normalize_pack_kernel, dim3(512), dim3(256), 0, stream,
                       zi, zj, packed, row_s, out);
    hipLaunchKernelGGL(simexp_kernel, dim3(2080), dim3(256), 0, stream,
                       packed, row_s, pos);
    hipLaunchKernelGGL(finalize_kernel, dim3(8), dim3(256), 0, stream, row_s, pos, out);
}

// Round 2
// 109.848 us; speedup vs baseline: 1.0643x; 1.0082x over previous
//
#include <hip/hip_runtime.h>
#include <hip/hip_bf16.h>
#include <stdint.h>

typedef short s16x8 __attribute__((ext_vector_type(8)));
typedef float f32x4 __attribute__((ext_vector_type(4)));

static constexpr int DDIM = 256;
static constexpr float TEN_LOG2E = 14.4269504088896340736f; // 10 * log2(e)

using u32_glb = __attribute__((address_space(1))) unsigned int;
using u32_lds = __attribute__((address_space(3))) unsigned int;

// ---------------- Kernel 1: normalize + pack into MFMA-fragment order ----------------
// 512 blocks x 256 threads; block g handles rows [16g, 16g+16). Output layout:
// packed[((g*8 + kt)*64 + lane)*8 .. +8] = bf16 P[16g + (lane&15)][kt*32 + (lane>>4)*8 ..]
// i.e. each (group, kt) fragment is one contiguous 1KB block in exact lane order, so a
// fragment load (or global_load_lds stage) in kernel 2 is a single coalesced
// 16B/lane segment. Also zero-inits row_s[8192] (blocks 0..7) and out[0] (block 0).
__global__ __launch_bounds__(256) void normalize_pack_kernel(
    const float* __restrict__ zi, const float* __restrict__ zj,
    ushort* __restrict__ packed, float* __restrict__ row_s, float* __restrict__ out)
{
    __shared__ ushort lds[16 * 256];

    if (blockIdx.x < 8) {
        ((float4*)row_s)[blockIdx.x * 256 + threadIdx.x] = (float4){0.f, 0.f, 0.f, 0.f};
        if (blockIdx.x == 0 && threadIdx.x == 0) out[0] = 0.0f;
    }

    const int t = threadIdx.x;
    const int r = t >> 4;            // 0..15: row within group
    const int c = t & 15;            // 16 threads per row
    const int row = blockIdx.x * 16 + r;
    const float* src = (row < 4096) ? (zi + (size_t)row * DDIM)
                                    : (zj + (size_t)(row - 4096) * DDIM);
    float4 v[4];
    #pragma unroll
    for (int j = 0; j < 4; ++j) v[j] = ((const float4*)src)[c + j * 16];

    float ss = 0.0f;
    #pragma unroll
    for (int j = 0; j < 4; ++j)
        ss += v[j].x * v[j].x + v[j].y * v[j].y + v[j].z * v[j].z + v[j].w * v[j].w;
    // reduce across the 16 lanes of this row (lanes of a row are contiguous)
    ss += __shfl_xor(ss, 1, 64);
    ss += __shfl_xor(ss, 2, 64);
    ss += __shfl_xor(ss, 4, 64);
    ss += __shfl_xor(ss, 8, 64);
    const float inv = 1.0f / fmaxf(sqrtf(ss), 1e-8f);

    #pragma unroll
    for (int j = 0; j < 4; ++j) {
        ushort4 o;
        o.x = __builtin_bit_cast(unsigned short, __float2bfloat16(v[j].x * inv));
        o.y = __builtin_bit_cast(unsigned short, __float2bfloat16(v[j].y * inv));
        o.z = __builtin_bit_cast(unsigned short, __float2bfloat16(v[j].z * inv));
        o.w = __builtin_bit_cast(unsigned short, __float2bfloat16(v[j].w * inv));
        *(ushort4*)(lds + r * 256 + (c + j * 16) * 4) = o;
    }
    __syncthreads();

    // repack: 8 kt x 64 lanes = 512 fragment-slots of 16B per block; 2 per thread
    #pragma unroll
    for (int h = 0; h < 2; ++h) {
        const int idx  = h * 256 + t;
        const int kt   = idx >> 6;
        const int lane = idx & 63;
        const int q    = lane >> 4;
        const int l15  = lane & 15;
        s16x8 frag = *(const s16x8*)(lds + l15 * 256 + kt * 32 + q * 8);
        ((s16x8*)packed)[(size_t)(blockIdx.x * 8 + kt) * 64 + lane] = frag;
    }
}

// ---------------- Kernel 2: upper-triangle Gram tiles, 3-deep ring + counted vmcnt ---
// 2080 blocks = 64*65/2 tiles of 128x128; 4 waves x (64x64 via 16x16x32 MFMA, 4x4
// frags). T3+T4 schedule: 3-deep LDS ring buffer, prefetch depth 2. Per kt: issue
// stage(kt+2) -> ds_read + MFMA on buf[kt%3] -> s_waitcnt vmcnt(4) (kt+1's loads
// landed, kt+2's 4 stay IN FLIGHT across the barrier) -> raw s_barrier. Never
// vmcnt(0) in the loop: loads get ~2 kt of slack instead of being drained every kt.
// Ring-of-3 makes one barrier/kt race-free: writes to buf[(kt+2)%3] are issued after
// barrier #(kt-1); that buffer's last reads (at kt-1) complete before that barrier
// (MFMA operand use forces the lgkmcnt wait first).
// Epilogue: row/col partials merged in LDS; one global atomic per row/col.
__global__ __launch_bounds__(256) void simexp_kernel(
    const ushort* __restrict__ packed,
    float* __restrict__ row_s,
    float* __restrict__ pos_out)
{
    // [ring 0..2][frag 0..15][512 ushorts = 1KB]; frags 0..7 = A groups, 8..15 = B
    __shared__ ushort sbuf[3][16][512];
    __shared__ float rsum_s[128];
    __shared__ float csum_s[128];

    const int tid  = threadIdx.x;
    const int w    = tid >> 6;
    const int lane = tid & 63;
    const int q    = lane >> 4;      // 0..3: K-octet / row-quad of the MFMA operand
    const int l15  = lane & 15;
    const int wm   = (w >> 1) * 64;  // wave row offset in 128x128 tile
    const int wn   = (w & 1) * 64;   // wave col offset

    // ---- upper-triangle decode: block b -> (ti, tj), ti <= tj ----
    const int b = blockIdx.x;
    int ti = (int)(64.5f - sqrtf(64.5f * 64.5f - 2.0f * (float)b));
    while ((ti + 1) * 64 - ((ti + 1) * ti) / 2 <= b) ++ti;
    while (ti * 64 - (ti * (ti - 1)) / 2 > b) --ti;
    const int tj = ti + (b - (ti * 64 - (ti * (ti - 1)) / 2));
    const int r0 = ti * 128, c0 = tj * 128;
    const bool diag  = (ti == tj);
    const bool ptile = (tj == ti + 32);  // contains positive-pair diagonal

    if (tid < 128) rsum_s[tid] = 0.0f;
    else           csum_s[tid - 128] = 0.0f;

    // per-wave staging sources: wave w stages fragments f = 4w..4w+3
    // f<8 -> A group (r0>>4)+f ; f>=8 -> B group (c0>>4)+(f-8)
    const int gA = r0 >> 4;
    const int gB = c0 >> 4;
    const ushort* sbase[4];
    #pragma unroll
    for (int s = 0; s < 4; ++s) {
        const int f = w * 4 + s;
        const int g = (f < 8) ? (gA + f) : (gB + (f - 8));
        sbase[s] = packed + (size_t)(g * 8) * 512 + (size_t)lane * 8;  // kt=0 fragment
    }

    auto stagek = [&](int buf, int kt) {
        #pragma unroll
        for (int s = 0; s < 4; ++s) {
            const int f = w * 4 + s;
            __builtin_amdgcn_global_load_lds(
                (const u32_glb*)(sbase[s] + kt * 512),
                (u32_lds*)&sbuf[buf][f][0],
                16, 0, 0);
        }
    };

    f32x4 acc[4][4];
    #pragma unroll
    for (int mi = 0; mi < 4; ++mi)
        #pragma unroll
        for (int ni = 0; ni < 4; ++ni)
            acc[mi][ni] = (f32x4){0.f, 0.f, 0.f, 0.f};

    // prologue: fill ring slots 0 and 1 (kt=0, kt=1); wait only for kt=0's 4 loads
    stagek(0, 0);
    stagek(1, 1);
    asm volatile("s_waitcnt vmcnt(4) lgkmcnt(0)" ::: "memory");
    __builtin_amdgcn_s_barrier();

    const int fa0 = (w >> 1) * 4;      // this wave's A fragment base
    const int fb0 = 8 + (w & 1) * 4;   // this wave's B fragment base

    #pragma unroll
    for (int kt = 0; kt < 8; ++kt) {
        if (kt + 2 < 8) stagek((kt + 2) % 3, kt + 2);  // 2-ahead prefetch

        s16x8 af[4], bfr[4];
        #pragma unroll
        for (int mi = 0; mi < 4; ++mi)
            af[mi] = *(const s16x8*)&sbuf[kt % 3][fa0 + mi][lane * 8];
        #pragma unroll
        for (int ni = 0; ni < 4; ++ni)
            bfr[ni] = *(const s16x8*)&sbuf[kt % 3][fb0 + ni][lane * 8];

        #pragma unroll
        for (int mi = 0; mi < 4; ++mi)
            #pragma unroll
            for (int ni = 0; ni < 4; ++ni)
                acc[mi][ni] = __builtin_amdgcn_mfma_f32_16x16x32_bf16(
                    af[mi], bfr[ni], acc[mi][ni], 0, 0, 0);

        if (kt < 7) {
            // counted wait: kt+1's 4 loads landed; kt+2's 4 (if any) stay in flight
            if (kt <= 5) asm volatile("s_waitcnt vmcnt(4)" ::: "memory");
            else         asm volatile("s_waitcnt vmcnt(0)" ::: "memory");
            __builtin_amdgcn_s_barrier();
        }
    }

    // ---- epilogue: exp, diag mask, positive extraction, row+col sums ----
    // C/D layout (16x16): col = lane&15, row = q*4 + r
    float rsum[4][4];
    float csum[4] = {0.f, 0.f, 0.f, 0.f};
    #pragma unroll
    for (int mi = 0; mi < 4; ++mi)
        #pragma unroll
        for (int r = 0; r < 4; ++r) rsum[mi][r] = 0.0f;

    #pragma unroll
    for (int mi = 0; mi < 4; ++mi)
        #pragma unroll
        for (int ni = 0; ni < 4; ++ni)
            #pragma unroll
            for (int r = 0; r < 4; ++r) {
                const int lr = wm + mi * 16 + q * 4 + r;
                const int lc = wn + ni * 16 + l15;
                float e = exp2f(acc[mi][ni][r] * TEN_LOG2E);
                if (diag && lr == lc) e = 0.0f;          // mask self-similarity
                rsum[mi][r] += e;
                csum[ni]    += e;
                if (ptile && lr == lc) {                 // positive pair: col = row + 4096
                    const float v = acc[mi][ni][r] * 10.0f;
                    pos_out[r0 + lr] = v;
                    pos_out[c0 + lr] = v;
                }
            }

    // row partials: reduce across the 16 lanes (cols) of each quad, merge via LDS
    #pragma unroll
    for (int mi = 0; mi < 4; ++mi)
        #pragma unroll
        for (int r = 0; r < 4; ++r) {
            float v = rsum[mi][r];
            v += __shfl_xor(v, 1, 64);
            v += __shfl_xor(v, 2, 64);
            v += __shfl_xor(v, 4, 64);
            v += __shfl_xor(v, 8, 64);
            if (l15 == 0)
                atomicAdd(&rsum_s[wm + mi * 16 + q * 4 + r], v);
        }

    // col partials (symmetric contribution): reduce across quads, merge via LDS
    if (!diag) {
        #pragma unroll
        for (int ni = 0; ni < 4; ++ni) {
            float v = csum[ni];
            v += __shfl_xor(v, 16, 64);
            v += __shfl_xor(v, 32, 64);
            if (q == 0)
                atomicAdd(&csum_s[wn + ni * 16 + l15], v);
        }
    }

    __syncthreads();

    // one global atomic per row (+ per col if off-diagonal): 128..256 lane-atomics/block
    if (tid < 128) {
        atomicAdd(&row_s[r0 + tid], rsum_s[tid]);
    } else if (!diag) {
        atomicAdd(&row_s[c0 + (tid - 128)], csum_s[tid - 128]);
    }
}

// ---------------- Kernel 3: finalize loss ----------------
__global__ __launch_bounds__(256) void finalize_kernel(
    const float* __restrict__ row_s, const float* __restrict__ pos,
    float* __restrict__ out)
{
    const int i = blockIdx.x * 256 + threadIdx.x;   // float4 index, 2048 total
    float4 s = ((const float4*)row_s)[i];
    float4 p = ((const float4*)pos)[i];
    float local = (__logf(s.x) - p.x) + (__logf(s.y) - p.y)
                + (__logf(s.z) - p.z) + (__logf(s.w) - p.w);
    #pragma unroll
    for (int off = 32; off > 0; off >>= 1) local += __shfl_xor(local, off, 64);
    __shared__ float red[4];
    if ((threadIdx.x & 63) == 0) red[threadIdx.x >> 6] = local;
    __syncthreads();
    if (threadIdx.x == 0)
        atomicAdd(out, (red[0] + red[1] + red[2] + red[3]) * (1.0f / 8192.0f));
}

// ---------------- Launch ----------------
extern "C" void kernel_launch(void* const* d_in, const int* in_sizes, int n_in,
                              void* d_out, int out_size, void* d_ws, size_t ws_size,
                              hipStream_t stream)
{
    const float* zi = (const float*)d_in[0];
    const float* zj = (const float*)d_in[1];

    ushort* packed = (ushort*)d_ws;                                    // 4 MB fragment-order bf16
    float* row_s   = (float*)((char*)d_ws + (4u << 20));               // 8192 fp32
    float* pos     = (float*)((char*)d_ws + (4u << 20) + (32u << 10)); // 8192 fp32
    float* out     = (float*)d_out;

    hipLaunchKernelGGL(normalize_pack_kernel, dim3(512), dim3(256), 0, stream,
                       zi, zj, packed, row_s, out);
    hipLaunchKernelGGL(simexp_kernel, dim3(2080), dim3(256), 0, stream,
                       packed, row_s, pos);
    hipLaunchKernelGGL(finalize_kernel, dim3(8), dim3(256), 0, stream, row_s, pos, out);
}